// Round 9
// baseline (314.814 us; speedup 1.0000x reference)
//
#include <hip/hip_runtime.h>
#include <math.h>

#define SEQ   512
#define RDIM  64
#define NB    64
#define SEGS  32
#define NSEG  2048   // NB*SEGS
#define STRD  12
#define WS_MATS_BYTES ((size_t)NSEG * RDIM * RDIM * sizeof(float))  // 32 MB

typedef short  v4s __attribute__((ext_vector_type(4)));
typedef float  v4f __attribute__((ext_vector_type(4)));
typedef unsigned int u32x2 __attribute__((ext_vector_type(2)));

__device__ __forceinline__ v4f mfma16(v4s a, v4s b, v4f c) {
#if __has_builtin(__builtin_amdgcn_mfma_f32_16x16x16bf16_1k)
    return __builtin_amdgcn_mfma_f32_16x16x16bf16_1k(a, b, c, 0, 0, 0);
#else
    v4f d;
    asm volatile("v_mfma_f32_16x16x16_bf16 %0, %1, %2, %3"
                 : "=v"(d) : "v"(a), "v"(b), "v"(c));
    return d;
#endif
}

__device__ __forceinline__ unsigned short bf16_rne(float x) {
    unsigned int u = __float_as_uint(x);
    unsigned int r = u + 0x7FFFu + ((u >> 16) & 1u);
    return (unsigned short)(r >> 16);
}
__device__ __forceinline__ float bf16_tof(unsigned short h) {
    return __uint_as_float(((unsigned int)h) << 16);
}

__device__ __forceinline__ float qreduce4(float x) {
#if __has_builtin(__builtin_amdgcn_permlane16_swap) && __has_builtin(__builtin_amdgcn_permlane32_swap)
    u32x2 a = __builtin_amdgcn_permlane16_swap(__float_as_uint(x), __float_as_uint(x), false, false);
    const float y = __uint_as_float(a.x) + __uint_as_float(a.y);
    u32x2 c = __builtin_amdgcn_permlane32_swap(__float_as_uint(y), __float_as_uint(y), false, false);
    return __uint_as_float(c.x) + __uint_as_float(c.y);
#else
    x += __shfl_xor(x, 16, 64);
    x += __shfl_xor(x, 32, 64);
    return x;
#endif
}

// ============ seg product for one wave (r8-proven body, parameterized) =======
__device__ __forceinline__ void seg_wave(const int* __restrict__ input_ids,
                                         const float* __restrict__ G_weight,
                                         float* __restrict__ ws,
                                         const int seg, const int lane)
{
    const int g   = lane >> 4;
    const int rl  = lane & 15;
    const int idb = seg << 4;

    v4f acc[4][4];
#pragma unroll
    for (int m = 0; m < 4; ++m)
#pragma unroll
        for (int jb = 0; jb < 4; ++jb)
#pragma unroll
            for (int r = 0; r < 4; ++r)
                acc[m][jb][r] = (m == jb && rl == ((g << 2) + r)) ? 1.0f : 0.0f;

    float4 pa[16];
    {
        const int id0 = __builtin_amdgcn_readfirstlane(input_ids[idb + 15]);
        const float* bp = G_weight + (((size_t)id0) << 12);
#pragma unroll
        for (int m = 0; m < 4; ++m) {
            const float* gp = bp + (((m << 4) + rl) << 6) + (g << 2);
#pragma unroll
            for (int kc = 0; kc < 4; ++kc)
                pa[(m << 2) + kc] = *(const float4*)(gp + (kc << 4));
        }
    }

    int pend = input_ids[idb + 14];

#pragma unroll 1
    for (int i = 0; i < 16; ++i) {
        v4s Bh[4][4], Bl[4][4];
#pragma unroll
        for (int kc = 0; kc < 4; ++kc)
#pragma unroll
            for (int jb = 0; jb < 4; ++jb) {
                v4s h, l;
#pragma unroll
                for (int r = 0; r < 4; ++r) {
                    const float x = acc[kc][jb][r];
                    const unsigned short hh = bf16_rne(x);
                    h[r] = (short)hh;
                    l[r] = (short)bf16_rne(x - bf16_tof(hh));
                }
                Bh[kc][jb] = h;
                Bl[kc][jb] = l;
            }

        const int idn = __builtin_amdgcn_readfirstlane(pend);

#pragma unroll
        for (int m = 0; m < 4; ++m) {
            v4s Ah[4], Al[4];
#pragma unroll
            for (int kc = 0; kc < 4; ++kc) {
                const float4 x = pa[(m << 2) + kc];
                const float e[4] = {x.x, x.y, x.z, x.w};
#pragma unroll
                for (int j = 0; j < 4; ++j) {
                    const unsigned short hh = bf16_rne(e[j]);
                    Ah[kc][j] = (short)hh;
                    Al[kc][j] = (short)bf16_rne(e[j] - bf16_tof(hh));
                }
            }
            if (i < 15) {
                const float* gp = G_weight + (((size_t)idn) << 12)
                                + (((m << 4) + rl) << 6) + (g << 2);
#pragma unroll
                for (int kc = 0; kc < 4; ++kc)
                    pa[(m << 2) + kc] = *(const float4*)(gp + (kc << 4));
            }
#pragma unroll
            for (int jb = 0; jb < 4; ++jb) {
                v4f d = {0.f, 0.f, 0.f, 0.f};
#pragma unroll
                for (int kc = 0; kc < 4; ++kc) {
                    d = mfma16(Ah[kc], Bh[kc][jb], d);
                    d = mfma16(Al[kc], Bh[kc][jb], d);
                    d = mfma16(Ah[kc], Bl[kc][jb], d);
                }
                acc[m][jb] = d;
            }
        }

        {
            int nx = 13 - i;
            nx = (nx < 0) ? 0 : nx;
            pend = input_ids[idb + nx];
        }
    }

    float* wp = ws + (((size_t)seg) << 12);
#pragma unroll
    for (int m = 0; m < 4; ++m)
#pragma unroll
        for (int jb = 0; jb < 4; ++jb)
#pragma unroll
            for (int r = 0; r < 4; ++r)
                wp[(((m << 4) + (g << 2) + r) << 6) + (jb << 4) + rl] = acc[m][jb][r];
}

// ============ 8-wave chain over 32 segment products (r7-proven body) =========
__device__ __forceinline__ void chain_and_out(const float* __restrict__ ws,
                                              const float* __restrict__ G1_weight,
                                              const float* __restrict__ lin_W,
                                              const float* __restrict__ lin_b,
                                              float* __restrict__ out,
                                              const int b, const int tid,
                                              float (*part)[RDIM][STRD])
{
    const int lane = tid & 63;
    const int w    = tid >> 6;
    const int sub  = lane >> 4;
    const int p16  = lane & 15;

    const int k0 = (w << 3) + sub;
    float vm0 = G1_weight[k0];
    float vm1 = G1_weight[k0 + 4];

    const size_t lo0 = (size_t)((w << 9) + (sub << 6) + (p16 << 2));
    const size_t lo1 = lo0 + 256;

    float4 bufA[16], bufB[16];

#define ISSUE2(S, T) do {                                                  \
        const float* bp_ = ws + (((size_t)((b << 5) + (T))) << 12);        \
        bufA[S] = *(const float4*)(bp_ + lo0);                             \
        bufB[S] = *(const float4*)(bp_ + lo1);                             \
    } while (0)

#pragma unroll
    for (int p = 0; p < 16; ++p) ISSUE2(p, p);

#define BODY2(S, T) do {                                                       \
        const float4 a_ = bufA[S];                                             \
        const float4 c_ = bufB[S];                                             \
        float fx = fmaf(vm0, a_.x, vm1 * c_.x);                                \
        float fy = fmaf(vm0, a_.y, vm1 * c_.y);                                \
        float fz = fmaf(vm0, a_.z, vm1 * c_.z);                                \
        float fw = fmaf(vm0, a_.w, vm1 * c_.w);                                \
        { int nx_ = (T) + 16; nx_ = (nx_ < SEGS) ? nx_ : (SEGS - 1);           \
          ISSUE2(S, nx_); }                                                    \
        fx = qreduce4(fx); fy = qreduce4(fy);                                  \
        fz = qreduce4(fz); fw = qreduce4(fw);                                  \
        const float wv_ = (sub == 0) ? fx : (sub == 1) ? fy                    \
                        : (sub == 2) ? fz : fw;                                \
        part[(T) & 1][(p16 << 2) + sub][w] = wv_;                              \
        asm volatile("s_waitcnt lgkmcnt(0)\n\ts_barrier" ::: "memory");        \
        {                                                                      \
            const float4* pk0_ = (const float4*)&part[(T) & 1][k0][0];         \
            const float4  r0_  = pk0_[0], r1_ = pk0_[1];                       \
            vm0 = ((r0_.x + r0_.y) + (r0_.z + r0_.w))                          \
                + ((r1_.x + r1_.y) + (r1_.z + r1_.w));                         \
            const float4* pk1_ = (const float4*)&part[(T) & 1][k0 + 4][0];     \
            const float4  s0_  = pk1_[0], s1_ = pk1_[1];                       \
            vm1 = ((s0_.x + s0_.y) + (s0_.z + s0_.w))                          \
                + ((s1_.x + s1_.y) + (s1_.z + s1_.w));                         \
        }                                                                      \
    } while (0)

    BODY2( 0,  0); BODY2( 1,  1); BODY2( 2,  2); BODY2( 3,  3);
    BODY2( 4,  4); BODY2( 5,  5); BODY2( 6,  6); BODY2( 7,  7);
    BODY2( 8,  8); BODY2( 9,  9); BODY2(10, 10); BODY2(11, 11);
    BODY2(12, 12); BODY2(13, 13); BODY2(14, 14); BODY2(15, 15);
    BODY2( 0, 16); BODY2( 1, 17); BODY2( 2, 18); BODY2( 3, 19);
    BODY2( 4, 20); BODY2( 5, 21); BODY2( 6, 22); BODY2( 7, 23);
    BODY2( 8, 24); BODY2( 9, 25); BODY2(10, 26); BODY2(11, 27);
    BODY2(12, 28); BODY2(13, 29); BODY2(14, 30); BODY2(15, 31);

#undef ISSUE2
#undef BODY2

    asm volatile("s_waitcnt vmcnt(0)" ::: "memory");

    float vj;
    {
        const float4* pj = (const float4*)&part[1][lane][0];
        const float4 q0 = pj[0], q1 = pj[1];
        vj = ((q0.x + q0.y) + (q0.z + q0.w)) + ((q1.x + q1.y) + (q1.z + q1.w));
    }

    if (w == 0) {
        float ss = vj * vj;
#pragma unroll
        for (int off = 32; off >= 1; off >>= 1)
            ss += __shfl_xor(ss, off, 64);
        const float inv = 1.0f / fmaxf(sqrtf(ss), 1e-12f);
        const float nj  = vj * inv;

        float d0 = nj * lin_W[lane];
        float d1 = nj * lin_W[RDIM + lane];
#pragma unroll
        for (int off = 32; off >= 1; off >>= 1) {
            d0 += __shfl_xor(d0, off, 64);
            d1 += __shfl_xor(d1, off, 64);
        }
        if (lane == 0) {
            out[b * 2 + 0] = d0 + lin_b[0];
            out[b * 2 + 1] = d1 + lin_b[1];
        }
    }
}

// ============ fused: seg products + per-batch counter + in-kernel chain ======
__global__ __launch_bounds__(512, 2)
void fused_kernel(const int* __restrict__ input_ids,
                  const float* __restrict__ G_weight,
                  const float* __restrict__ G1_weight,
                  const float* __restrict__ lin_W,
                  const float* __restrict__ lin_b,
                  float* __restrict__ ws,
                  int* __restrict__ cnt,
                  float* __restrict__ out)
{
    __shared__ __align__(16) float part[2][RDIM][STRD];

    const int tid  = threadIdx.x;
    const int lane = tid & 63;
    const int w    = tid >> 6;
    const int blk  = blockIdx.x;
    const int seg  = (blk << 3) + w;     // 256 blocks x 8 waves = 2048 segments

    seg_wave(input_ids, G_weight, ws, seg, lane);

    __threadfence();  // wave-level: drains this wave's ws stores, flushes L2
    if (lane == 0)
        __hip_atomic_fetch_add(&cnt[seg >> 5], 1,
                               __ATOMIC_RELEASE, __HIP_MEMORY_SCOPE_AGENT);

    if (blk < NB) {
        const int* cp = &cnt[blk];
        while (__hip_atomic_load(cp, __ATOMIC_ACQUIRE,
                                 __HIP_MEMORY_SCOPE_AGENT) < SEGS)
            __builtin_amdgcn_s_sleep(8);
        __threadfence();
        __syncthreads();
        chain_and_out(ws, G1_weight, lin_W, lin_b, out, blk, tid, part);
    }
}

// ============ fallback two-kernel path (r8-proven) ===========================
__global__ __launch_bounds__(64, 2)
void seg_kernel(const int* __restrict__ input_ids,
                const float* __restrict__ G_weight,
                float* __restrict__ ws)
{
    seg_wave(input_ids, G_weight, ws, blockIdx.x, threadIdx.x & 63);
}

__global__ __launch_bounds__(512, 2)
void chain2_kernel(const float* __restrict__ ws,
                   const float* __restrict__ G1_weight,
                   const float* __restrict__ lin_W,
                   const float* __restrict__ lin_b,
                   float* __restrict__ out)
{
    __shared__ __align__(16) float part[2][RDIM][STRD];
    chain_and_out(ws, G1_weight, lin_W, lin_b, out, blockIdx.x, threadIdx.x, part);
}

// ============ last-resort fallback: round-5 single-kernel chain ==============
__global__ __launch_bounds__(512, 2)
void matchain_kernel(const int* __restrict__ input_ids,
                     const float* __restrict__ G_weight,
                     const float* __restrict__ G1_weight,
                     const float* __restrict__ lin_W,
                     const float* __restrict__ lin_b,
                     float* __restrict__ out)
{
    __shared__ int   ids[SEQ];
    __shared__ __align__(16) float part[2][RDIM][STRD];

    const int tid  = threadIdx.x;
    const int lane = tid & 63;
    const int w    = tid >> 6;
    const int b    = blockIdx.x;
    const int sub  = lane >> 4;
    const int p16  = lane & 15;

    ids[tid] = input_ids[b * SEQ + tid];
    __syncthreads();

    const int k0 = (w << 3) + sub;
    float vm0 = G1_weight[k0];
    float vm1 = G1_weight[k0 + 4];

    const size_t lo0 = (size_t)((w << 9) + (sub << 6) + (p16 << 2));
    const size_t lo1 = lo0 + 256;

    float4 bufA[16], bufB[16];

#define ISSUE(S, id_) do {                                        \
        const float* bp_ = G_weight + (((size_t)(id_)) << 12);    \
        bufA[S] = *(const float4*)(bp_ + lo0);                    \
        bufB[S] = *(const float4*)(bp_ + lo1);                    \
    } while (0)

#pragma unroll
    for (int p = 0; p < 16; ++p)
        ISSUE(p, __builtin_amdgcn_readfirstlane(ids[p]));

    int pend = ids[16];

#define BODY(S, K) do {                                                        \
        const float4 a_ = bufA[S];                                             \
        const float4 c_ = bufB[S];                                             \
        float fx = fmaf(vm0, a_.x, vm1 * c_.x);                                \
        float fy = fmaf(vm0, a_.y, vm1 * c_.y);                                \
        float fz = fmaf(vm0, a_.z, vm1 * c_.z);                                \
        float fw = fmaf(vm0, a_.w, vm1 * c_.w);                                \
        {                                                                      \
            const int idn_ = __builtin_amdgcn_readfirstlane(pend);             \
            ISSUE(S, idn_);                                                    \
            int nx_ = t0 + (K) + 17;                                           \
            nx_ = (nx_ < SEQ) ? nx_ : (SEQ - 1);                               \
            pend = ids[nx_];                                                   \
        }                                                                      \
        fx = qreduce4(fx); fy = qreduce4(fy);                                  \
        fz = qreduce4(fz); fw = qreduce4(fw);                                  \
        const float wv_ = (sub == 0) ? fx : (sub == 1) ? fy                    \
                        : (sub == 2) ? fz : fw;                                \
        part[(K) & 1][(p16 << 2) + sub][w] = wv_;                              \
        asm volatile("s_waitcnt lgkmcnt(0)\n\ts_barrier" ::: "memory");        \
        {                                                                      \
            const float4* pk0_ = (const float4*)&part[(K) & 1][k0][0];         \
            const float4  r0_  = pk0_[0], r1_ = pk0_[1];                       \
            vm0 = ((r0_.x + r0_.y) + (r0_.z + r0_.w))                          \
                + ((r1_.x + r1_.y) + (r1_.z + r1_.w));                         \
            const float4* pk1_ = (const float4*)&part[(K) & 1][k0 + 4][0];     \
            const float4  s0_  = pk1_[0], s1_ = pk1_[1];                       \
            vm1 = ((s0_.x + s0_.y) + (s0_.z + s0_.w))                          \
                + ((s1_.x + s1_.y) + (s1_.z + s1_.w));                         \
        }                                                                      \
    } while (0)

#pragma unroll 1
    for (int t0 = 0; t0 < SEQ; t0 += 16) {
        BODY( 0,  0); BODY( 1,  1); BODY( 2,  2); BODY( 3,  3);
        BODY( 4,  4); BODY( 5,  5); BODY( 6,  6); BODY( 7,  7);
        BODY( 8,  8); BODY( 9,  9); BODY(10, 10); BODY(11, 11);
        BODY(12, 12); BODY(13, 13); BODY(14, 14); BODY(15, 15);
    }
#undef ISSUE
#undef BODY

    asm volatile("s_waitcnt vmcnt(0)" ::: "memory");

    float vj;
    {
        const float4* pj = (const float4*)&part[1][lane][0];
        const float4 q0 = pj[0], q1 = pj[1];
        vj = ((q0.x + q0.y) + (q0.z + q0.w)) + ((q1.x + q1.y) + (q1.z + q1.w));
    }

    if (w == 0) {
        float ss = vj * vj;
#pragma unroll
        for (int off = 32; off >= 1; off >>= 1)
            ss += __shfl_xor(ss, off, 64);
        const float inv = 1.0f / fmaxf(sqrtf(ss), 1e-12f);
        const float nj  = vj * inv;

        float d0 = nj * lin_W[lane];
        float d1 = nj * lin_W[RDIM + lane];
#pragma unroll
        for (int off = 32; off >= 1; off >>= 1) {
            d0 += __shfl_xor(d0, off, 64);
            d1 += __shfl_xor(d1, off, 64);
        }
        if (lane == 0) {
            out[b * 2 + 0] = d0 + lin_b[0];
            out[b * 2 + 1] = d1 + lin_b[1];
        }
    }
}

extern "C" void kernel_launch(void* const* d_in, const int* in_sizes, int n_in,
                              void* d_out, int out_size, void* d_ws, size_t ws_size,
                              hipStream_t stream) {
    const int*   input_ids = (const int*)d_in[0];
    // d_in[1] = mask, d_in[2] = segment_ids, d_in[3] = seq_lengths — unused
    const float* G_weight  = (const float*)d_in[4];
    const float* G1_weight = (const float*)d_in[5];
    const float* lin_W     = (const float*)d_in[6];
    const float* lin_b     = (const float*)d_in[7];
    float*       out       = (float*)d_out;

    const size_t need_fused = WS_MATS_BYTES + 4096;
    if (ws_size >= need_fused) {
        float* ws  = (float*)d_ws;
        int*   cnt = (int*)((char*)d_ws + WS_MATS_BYTES);
        hipMemsetAsync(cnt, 0, NB * sizeof(int), stream);
        fused_kernel<<<NSEG / 8, 512, 0, stream>>>(input_ids, G_weight, G1_weight,
                                                   lin_W, lin_b, ws, cnt, out);
    } else if (ws_size >= WS_MATS_BYTES) {
        float* ws = (float*)d_ws;
        seg_kernel<<<NSEG, 64, 0, stream>>>(input_ids, G_weight, ws);
        chain2_kernel<<<NB, 512, 0, stream>>>(ws, G1_weight, lin_W, lin_b, out);
    } else {
        matchain_kernel<<<NB, 512, 0, stream>>>(input_ids, G_weight, G1_weight,
                                                lin_W, lin_b, out);
    }
}

// Round 10
// 106.789 us; speedup vs baseline: 2.9480x; 2.9480x over previous
//
#include <hip/hip_runtime.h>
#include <math.h>

#define SEQ   512
#define RDIM  64
#define NB    64
#define SEGS  32
#define NSEG  2048   // NB*SEGS
#define STRD  12
#define WS_MATS_BYTES ((size_t)NSEG * RDIM * RDIM * sizeof(float))  // 32 MB

typedef short  v4s __attribute__((ext_vector_type(4)));
typedef float  v4f __attribute__((ext_vector_type(4)));
typedef unsigned int u32x2 __attribute__((ext_vector_type(2)));

__device__ __forceinline__ v4f mfma16(v4s a, v4s b, v4f c) {
#if __has_builtin(__builtin_amdgcn_mfma_f32_16x16x16bf16_1k)
    return __builtin_amdgcn_mfma_f32_16x16x16bf16_1k(a, b, c, 0, 0, 0);
#else
    v4f d;
    asm volatile("v_mfma_f32_16x16x16_bf16 %0, %1, %2, %3"
                 : "=v"(d) : "v"(a), "v"(b), "v"(c));
    return d;
#endif
}

// split two fp32 into packed bf16 hi-pair and lo-pair (6 VALU ops / 2 elems):
// hp = [bf16(x0) | bf16(x1)<<16], lp = [bf16(x0-hi0) | bf16(x1-hi1)<<16]
__device__ __forceinline__ u32x2 split2(float x0, float x1) {
    unsigned int hp;
    asm("v_cvt_pk_bf16_f32 %0, %1, %2" : "=v"(hp) : "v"(x0), "v"(x1));
    const float h0 = __uint_as_float(hp << 16);
    const float h1 = __uint_as_float(hp & 0xffff0000u);
    unsigned int lp;
    asm("v_cvt_pk_bf16_f32 %0, %1, %2" : "=v"(lp) : "v"(x0 - h0), "v"(x1 - h1));
    u32x2 r; r.x = hp; r.y = lp;
    return r;
}

__device__ __forceinline__ v4s mk4(unsigned int a, unsigned int b) {
    u32x2 t; t.x = a; t.y = b;
    return __builtin_bit_cast(v4s, t);
}

__device__ __forceinline__ float qreduce4(float x) {
#if __has_builtin(__builtin_amdgcn_permlane16_swap) && __has_builtin(__builtin_amdgcn_permlane32_swap)
    u32x2 a = __builtin_amdgcn_permlane16_swap(__float_as_uint(x), __float_as_uint(x), false, false);
    const float y = __uint_as_float(a.x) + __uint_as_float(a.y);
    u32x2 c = __builtin_amdgcn_permlane32_swap(__float_as_uint(y), __float_as_uint(y), false, false);
    return __uint_as_float(c.x) + __uint_as_float(c.y);
#else
    x += __shfl_xor(x, 16, 64);
    x += __shfl_xor(x, 32, 64);
    return x;
#endif
}

// ============ Phase 1: one wave per segment (r8 body + cvt_pk splits) ========
__global__ __launch_bounds__(64, 2)
void seg_kernel(const int* __restrict__ input_ids,
                const float* __restrict__ G_weight,
                float* __restrict__ ws)
{
    const int lane = threadIdx.x & 63;
    const int g    = lane >> 4;
    const int rl   = lane & 15;
    const int seg  = blockIdx.x;
    const int idb  = seg << 4;

    // acc tile (m, jb): element (16m + 4g + r, 16jb + rl). Init Q = I.
    v4f acc[4][4];
#pragma unroll
    for (int m = 0; m < 4; ++m)
#pragma unroll
        for (int jb = 0; jb < 4; ++jb)
#pragma unroll
            for (int r = 0; r < 4; ++r)
                acc[m][jb][r] = (m == jb && rl == ((g << 2) + r)) ? 1.0f : 0.0f;

    // full-A register buffer: pa[4m+kc] = A[16m+rl][16kc+4g .. +3]
    float4 pa[16];
    {
        const int id0 = __builtin_amdgcn_readfirstlane(input_ids[idb + 15]);
        const float* bp = G_weight + (((size_t)id0) << 12);
#pragma unroll
        for (int m = 0; m < 4; ++m) {
            const float* gp = bp + (((m << 4) + rl) << 6) + (g << 2);
#pragma unroll
            for (int kc = 0; kc < 4; ++kc)
                pa[(m << 2) + kc] = *(const float4*)(gp + (kc << 4));
        }
    }

    int pend = input_ids[idb + 14];

#pragma unroll 1
    for (int i = 0; i < 16; ++i) {
        // 1) B-split: acc -> Bh/Bl via cvt_pk (before acc regs become new D)
        v4s Bh[4][4], Bl[4][4];
#pragma unroll
        for (int kc = 0; kc < 4; ++kc)
#pragma unroll
            for (int jb = 0; jb < 4; ++jb) {
                const v4f x = acc[kc][jb];
                const u32x2 p01 = split2(x[0], x[1]);
                const u32x2 p23 = split2(x[2], x[3]);
                Bh[kc][jb] = mk4(p01.x, p23.x);
                Bl[kc][jb] = mk4(p01.y, p23.y);
            }

        const int idn = __builtin_amdgcn_readfirstlane(pend);

        // 2) per row-stripe m: split A, re-issue loads for next matrix, MFMA
#pragma unroll
        for (int m = 0; m < 4; ++m) {
            v4s Ah[4], Al[4];
#pragma unroll
            for (int kc = 0; kc < 4; ++kc) {
                const float4 x = pa[(m << 2) + kc];
                const u32x2 p01 = split2(x.x, x.y);
                const u32x2 p23 = split2(x.z, x.w);
                Ah[kc] = mk4(p01.x, p23.x);
                Al[kc] = mk4(p01.y, p23.y);
            }
            if (i < 15) {
                const float* gp = G_weight + (((size_t)idn) << 12)
                                + (((m << 4) + rl) << 6) + (g << 2);
#pragma unroll
                for (int kc = 0; kc < 4; ++kc)
                    pa[(m << 2) + kc] = *(const float4*)(gp + (kc << 4));
            }
#pragma unroll
            for (int jb = 0; jb < 4; ++jb) {
                v4f d = {0.f, 0.f, 0.f, 0.f};
#pragma unroll
                for (int kc = 0; kc < 4; ++kc) {
                    d = mfma16(Ah[kc], Bh[kc][jb], d);
                    d = mfma16(Al[kc], Bh[kc][jb], d);
                    d = mfma16(Ah[kc], Bl[kc][jb], d);
                }
                acc[m][jb] = d;
            }
        }

        {
            int nx = 13 - i;
            nx = (nx < 0) ? 0 : nx;
            pend = input_ids[idb + nx];
        }
    }

    float* wp = ws + (((size_t)seg) << 12);
#pragma unroll
    for (int m = 0; m < 4; ++m)
#pragma unroll
        for (int jb = 0; jb < 4; ++jb)
#pragma unroll
            for (int r = 0; r < 4; ++r)
                wp[(((m << 4) + (g << 2) + r) << 6) + (jb << 4) + rl] = acc[m][jb][r];
}

// ============ Phase 2: 8-wave chain over 32 segment products (r7 body) =======
__device__ __forceinline__ void chain_and_out(const float* __restrict__ ws,
                                              const float* __restrict__ G1_weight,
                                              const float* __restrict__ lin_W,
                                              const float* __restrict__ lin_b,
                                              float* __restrict__ out,
                                              const int b, const int tid,
                                              float (*part)[RDIM][STRD])
{
    const int lane = tid & 63;
    const int w    = tid >> 6;
    const int sub  = lane >> 4;
    const int p16  = lane & 15;

    const int k0 = (w << 3) + sub;
    float vm0 = G1_weight[k0];
    float vm1 = G1_weight[k0 + 4];

    const size_t lo0 = (size_t)((w << 9) + (sub << 6) + (p16 << 2));
    const size_t lo1 = lo0 + 256;

    float4 bufA[16], bufB[16];

#define ISSUE2(S, T) do {                                                  \
        const float* bp_ = ws + (((size_t)((b << 5) + (T))) << 12);        \
        bufA[S] = *(const float4*)(bp_ + lo0);                             \
        bufB[S] = *(const float4*)(bp_ + lo1);                             \
    } while (0)

#pragma unroll
    for (int p = 0; p < 16; ++p) ISSUE2(p, p);

#define BODY2(S, T) do {                                                       \
        const float4 a_ = bufA[S];                                             \
        const float4 c_ = bufB[S];                                             \
        float fx = fmaf(vm0, a_.x, vm1 * c_.x);                                \
        float fy = fmaf(vm0, a_.y, vm1 * c_.y);                                \
        float fz = fmaf(vm0, a_.z, vm1 * c_.z);                                \
        float fw = fmaf(vm0, a_.w, vm1 * c_.w);                                \
        { int nx_ = (T) + 16; nx_ = (nx_ < SEGS) ? nx_ : (SEGS - 1);           \
          ISSUE2(S, nx_); }                                                    \
        fx = qreduce4(fx); fy = qreduce4(fy);                                  \
        fz = qreduce4(fz); fw = qreduce4(fw);                                  \
        const float wv_ = (sub == 0) ? fx : (sub == 1) ? fy                    \
                        : (sub == 2) ? fz : fw;                                \
        part[(T) & 1][(p16 << 2) + sub][w] = wv_;                              \
        asm volatile("s_waitcnt lgkmcnt(0)\n\ts_barrier" ::: "memory");        \
        {                                                                      \
            const float4* pk0_ = (const float4*)&part[(T) & 1][k0][0];         \
            const float4  r0_  = pk0_[0], r1_ = pk0_[1];                       \
            vm0 = ((r0_.x + r0_.y) + (r0_.z + r0_.w))                          \
                + ((r1_.x + r1_.y) + (r1_.z + r1_.w));                         \
            const float4* pk1_ = (const float4*)&part[(T) & 1][k0 + 4][0];     \
            const float4  s0_  = pk1_[0], s1_ = pk1_[1];                       \
            vm1 = ((s0_.x + s0_.y) + (s0_.z + s0_.w))                          \
                + ((s1_.x + s1_.y) + (s1_.z + s1_.w));                         \
        }                                                                      \
    } while (0)

    BODY2( 0,  0); BODY2( 1,  1); BODY2( 2,  2); BODY2( 3,  3);
    BODY2( 4,  4); BODY2( 5,  5); BODY2( 6,  6); BODY2( 7,  7);
    BODY2( 8,  8); BODY2( 9,  9); BODY2(10, 10); BODY2(11, 11);
    BODY2(12, 12); BODY2(13, 13); BODY2(14, 14); BODY2(15, 15);
    BODY2( 0, 16); BODY2( 1, 17); BODY2( 2, 18); BODY2( 3, 19);
    BODY2( 4, 20); BODY2( 5, 21); BODY2( 6, 22); BODY2( 7, 23);
    BODY2( 8, 24); BODY2( 9, 25); BODY2(10, 26); BODY2(11, 27);
    BODY2(12, 28); BODY2(13, 29); BODY2(14, 30); BODY2(15, 31);

#undef ISSUE2
#undef BODY2

    asm volatile("s_waitcnt vmcnt(0)" ::: "memory");

    float vj;
    {
        const float4* pj = (const float4*)&part[1][lane][0];
        const float4 q0 = pj[0], q1 = pj[1];
        vj = ((q0.x + q0.y) + (q0.z + q0.w)) + ((q1.x + q1.y) + (q1.z + q1.w));
    }

    if (w == 0) {
        float ss = vj * vj;
#pragma unroll
        for (int off = 32; off >= 1; off >>= 1)
            ss += __shfl_xor(ss, off, 64);
        const float inv = 1.0f / fmaxf(sqrtf(ss), 1e-12f);
        const float nj  = vj * inv;

        float d0 = nj * lin_W[lane];
        float d1 = nj * lin_W[RDIM + lane];
#pragma unroll
        for (int off = 32; off >= 1; off >>= 1) {
            d0 += __shfl_xor(d0, off, 64);
            d1 += __shfl_xor(d1, off, 64);
        }
        if (lane == 0) {
            out[b * 2 + 0] = d0 + lin_b[0];
            out[b * 2 + 1] = d1 + lin_b[1];
        }
    }
}

__global__ __launch_bounds__(512, 2)
void chain2_kernel(const float* __restrict__ ws,
                   const float* __restrict__ G1_weight,
                   const float* __restrict__ lin_W,
                   const float* __restrict__ lin_b,
                   float* __restrict__ out)
{
    __shared__ __align__(16) float part[2][RDIM][STRD];
    chain_and_out(ws, G1_weight, lin_W, lin_b, out, blockIdx.x, threadIdx.x, part);
}

// ============ fallback: round-5 single-kernel chain (ws too small) ===========
__global__ __launch_bounds__(512, 2)
void matchain_kernel(const int* __restrict__ input_ids,
                     const float* __restrict__ G_weight,
                     const float* __restrict__ G1_weight,
                     const float* __restrict__ lin_W,
                     const float* __restrict__ lin_b,
                     float* __restrict__ out)
{
    __shared__ int   ids[SEQ];
    __shared__ __align__(16) float part[2][RDIM][STRD];

    const int tid  = threadIdx.x;
    const int lane = tid & 63;
    const int w    = tid >> 6;
    const int b    = blockIdx.x;
    const int sub  = lane >> 4;
    const int p16  = lane & 15;

    ids[tid] = input_ids[b * SEQ + tid];
    __syncthreads();

    const int k0 = (w << 3) + sub;
    float vm0 = G1_weight[k0];
    float vm1 = G1_weight[k0 + 4];

    const size_t lo0 = (size_t)((w << 9) + (sub << 6) + (p16 << 2));
    const size_t lo1 = lo0 + 256;

    float4 bufA[16], bufB[16];

#define ISSUE(S, id_) do {                                        \
        const float* bp_ = G_weight + (((size_t)(id_)) << 12);    \
        bufA[S] = *(const float4*)(bp_ + lo0);                    \
        bufB[S] = *(const float4*)(bp_ + lo1);                    \
    } while (0)

#pragma unroll
    for (int p = 0; p < 16; ++p)
        ISSUE(p, __builtin_amdgcn_readfirstlane(ids[p]));

    int pend = ids[16];

#define BODY(S, K) do {                                                        \
        const float4 a_ = bufA[S];                                             \
        const float4 c_ = bufB[S];                                             \
        float fx = fmaf(vm0, a_.x, vm1 * c_.x);                                \
        float fy = fmaf(vm0, a_.y, vm1 * c_.y);                                \
        float fz = fmaf(vm0, a_.z, vm1 * c_.z);                                \
        float fw = fmaf(vm0, a_.w, vm1 * c_.w);                                \
        {                                                                      \
            const int idn_ = __builtin_amdgcn_readfirstlane(pend);             \
            ISSUE(S, idn_);                                                    \
            int nx_ = t0 + (K) + 17;                                           \
            nx_ = (nx_ < SEQ) ? nx_ : (SEQ - 1);                               \
            pend = ids[nx_];                                                   \
        }                                                                      \
        fx = qreduce4(fx); fy = qreduce4(fy);                                  \
        fz = qreduce4(fz); fw = qreduce4(fw);                                  \
        const float wv_ = (sub == 0) ? fx : (sub == 1) ? fy                    \
                        : (sub == 2) ? fz : fw;                                \
        part[(K) & 1][(p16 << 2) + sub][w] = wv_;                              \
        asm volatile("s_waitcnt lgkmcnt(0)\n\ts_barrier" ::: "memory");        \
        {                                                                      \
            const float4* pk0_ = (const float4*)&part[(K) & 1][k0][0];         \
            const float4  r0_  = pk0_[0], r1_ = pk0_[1];                       \
            vm0 = ((r0_.x + r0_.y) + (r0_.z + r0_.w))                          \
                + ((r1_.x + r1_.y) + (r1_.z + r1_.w));                         \
            const float4* pk1_ = (const float4*)&part[(K) & 1][k0 + 4][0];     \
            const float4  s0_  = pk1_[0], s1_ = pk1_[1];                       \
            vm1 = ((s0_.x + s0_.y) + (s0_.z + s0_.w))                          \
                + ((s1_.x + s1_.y) + (s1_.z + s1_.w));                         \
        }                                                                      \
    } while (0)

#pragma unroll 1
    for (int t0 = 0; t0 < SEQ; t0 += 16) {
        BODY( 0,  0); BODY( 1,  1); BODY( 2,  2); BODY( 3,  3);
        BODY( 4,  4); BODY( 5,  5); BODY( 6,  6); BODY( 7,  7);
        BODY( 8,  8); BODY( 9,  9); BODY(10, 10); BODY(11, 11);
        BODY(12, 12); BODY(13, 13); BODY(14, 14); BODY(15, 15);
    }
#undef ISSUE
#undef BODY

    asm volatile("s_waitcnt vmcnt(0)" ::: "memory");

    float vj;
    {
        const float4* pj = (const float4*)&part[1][lane][0];
        const float4 q0 = pj[0], q1 = pj[1];
        vj = ((q0.x + q0.y) + (q0.z + q0.w)) + ((q1.x + q1.y) + (q1.z + q1.w));
    }

    if (w == 0) {
        float ss = vj * vj;
#pragma unroll
        for (int off = 32; off >= 1; off >>= 1)
            ss += __shfl_xor(ss, off, 64);
        const float inv = 1.0f / fmaxf(sqrtf(ss), 1e-12f);
        const float nj  = vj * inv;

        float d0 = nj * lin_W[lane];
        float d1 = nj * lin_W[RDIM + lane];
#pragma unroll
        for (int off = 32; off >= 1; off >>= 1) {
            d0 += __shfl_xor(d0, off, 64);
            d1 += __shfl_xor(d1, off, 64);
        }
        if (lane == 0) {
            out[b * 2 + 0] = d0 + lin_b[0];
            out[b * 2 + 1] = d1 + lin_b[1];
        }
    }
}

extern "C" void kernel_launch(void* const* d_in, const int* in_sizes, int n_in,
                              void* d_out, int out_size, void* d_ws, size_t ws_size,
                              hipStream_t stream) {
    const int*   input_ids = (const int*)d_in[0];
    // d_in[1] = mask, d_in[2] = segment_ids, d_in[3] = seq_lengths — unused
    const float* G_weight  = (const float*)d_in[4];
    const float* G1_weight = (const float*)d_in[5];
    const float* lin_W     = (const float*)d_in[6];
    const float* lin_b     = (const float*)d_in[7];
    float*       out       = (float*)d_out;

    if (ws_size >= WS_MATS_BYTES) {
        float* ws = (float*)d_ws;
        seg_kernel<<<NSEG, 64, 0, stream>>>(input_ids, G_weight, ws);
        chain2_kernel<<<NB, 512, 0, stream>>>(ws, G1_weight, lin_W, lin_b, out);
    } else {
        matchain_kernel<<<NB, 512, 0, stream>>>(input_ids, G_weight, G1_weight,
                                                lin_W, lin_b, out);
    }
}